// Round 3
// baseline (404.405 us; speedup 1.0000x reference)
//
#include <hip/hip_runtime.h>
#include <stdint.h>

#define N_SEQ 4096
#define C_DIM 768
#define HEADS 12
#define HD    64
#define OI    (2304*768)

typedef __attribute__((ext_vector_type(8))) short short8;
typedef __attribute__((ext_vector_type(4))) float f32x4;

__device__ __forceinline__ short f2bf(float f) {
  union { float f; unsigned u; } v; v.f = f;
  unsigned r = v.u + 0x7FFF + ((v.u >> 16) & 1);   // RNE
  return (short)(r >> 16);
}
__device__ __forceinline__ short f2bf_trunc(float f) {
  union { float f; unsigned u; } v; v.f = f;
  return (short)(v.u >> 16);                       // truncate (p>0, err<0.4%)
}

// ---------------- kernel A: combine templates -> bf16 qkv_w (2304x768) -------
__global__ __launch_bounds__(256) void prep_qkvw(const float* __restrict__ tmpl,
                                                 const float* __restrict__ coeffs,
                                                 short* __restrict__ w_bf) {
  __shared__ float c[16];
  if (threadIdx.x < 16)
    c[threadIdx.x] = 0.5f * (coeffs[threadIdx.x] + coeffs[16 + threadIdx.x]);
  __syncthreads();
  int idx = blockIdx.x * 256 + threadIdx.x;
  int base = idx * 4;
  if (base >= OI) return;
  float ax = 0.f, ay = 0.f, az = 0.f, aw = 0.f;
#pragma unroll
  for (int t = 0; t < 16; ++t) {
    float4 v = *(const float4*)(tmpl + (size_t)t * OI + base);
    float ct = c[t];
    ax = fmaf(ct, v.x, ax); ay = fmaf(ct, v.y, ay);
    az = fmaf(ct, v.z, az); aw = fmaf(ct, v.w, aw);
  }
  short4 o = make_short4(f2bf(ax), f2bf(ay), f2bf(az), f2bf(aw));
  *(short4*)(w_bf + base) = o;
}

// ---------------- kernel B: fp32 -> bf16 cast (n4 float4 groups) -------------
__global__ __launch_bounds__(256) void cvt_bf16(const float* __restrict__ src,
                                                short* __restrict__ dst, int n4) {
  int i = blockIdx.x * 256 + threadIdx.x;
  if (i >= n4) return;
  float4 v = ((const float4*)src)[i];
  ((short4*)dst)[i] = make_short4(f2bf(v.x), f2bf(v.y), f2bf(v.z), f2bf(v.w));
}

// ---------------- kernel C/E: 128x128 bf16 MFMA GEMM, C = A * B^T ------------
// MODE 0 epilogue: q -> [h][n][d] (pre-scaled 0.125*log2e), k -> [h][n][d],
//                  v -> TRANSPOSED [h][d][n]
// MODE 1 epilogue: fp32 C (ldc) + bias.
#define GST 40   // LDS row stride (32 + 8 pad) elements
#define QSCALE 0.1803368801111204f   // 0.125 * log2(e): exp2 directly on logits
template<int MODE>
__global__ __launch_bounds__(256) void gemm_bt(const short* __restrict__ A,
                                               const short* __restrict__ B,
                                               const float* __restrict__ bias,
                                               short* __restrict__ qkv_out,
                                               float* __restrict__ c_out,
                                               int K, int ldc) {
  __shared__ short As[128 * GST];
  __shared__ short Bs[128 * GST];
  int tid = threadIdx.x;
  int wave = tid >> 6, lane = tid & 63, g = lane >> 4, l15 = lane & 15;
  int wm = (wave >> 1) * 64, wn = (wave & 1) * 64;
  size_t mblk = (size_t)blockIdx.x * 128;
  size_t nblk = (size_t)blockIdx.y * 128;

  f32x4 acc[4][4];
#pragma unroll
  for (int mi = 0; mi < 4; ++mi)
#pragma unroll
    for (int ni = 0; ni < 4; ++ni)
#pragma unroll
      for (int r = 0; r < 4; ++r) acc[mi][ni][r] = 0.f;

  int row0 = tid >> 2;          // 0..63
  int c8   = (tid & 3) * 8;     // 0,8,16,24

  for (int k0 = 0; k0 < K; k0 += 32) {
    short8 a0 = *(const short8*)(A + (mblk + row0) * K + k0 + c8);
    short8 a1 = *(const short8*)(A + (mblk + row0 + 64) * K + k0 + c8);
    short8 b0 = *(const short8*)(B + (nblk + row0) * K + k0 + c8);
    short8 b1 = *(const short8*)(B + (nblk + row0 + 64) * K + k0 + c8);
    __syncthreads();   // previous iteration's frag reads done
    *(short8*)(As + row0 * GST + c8) = a0;
    *(short8*)(As + (row0 + 64) * GST + c8) = a1;
    *(short8*)(Bs + row0 * GST + c8) = b0;
    *(short8*)(Bs + (row0 + 64) * GST + c8) = b1;
    __syncthreads();
    short8 af[4], bfr[4];
#pragma unroll
    for (int mi = 0; mi < 4; ++mi)
      af[mi] = *(const short8*)(As + (wm + mi * 16 + l15) * GST + g * 8);
#pragma unroll
    for (int ni = 0; ni < 4; ++ni)
      bfr[ni] = *(const short8*)(Bs + (wn + ni * 16 + l15) * GST + g * 8);
#pragma unroll
    for (int mi = 0; mi < 4; ++mi)
#pragma unroll
      for (int ni = 0; ni < 4; ++ni)
        acc[mi][ni] = __builtin_amdgcn_mfma_f32_16x16x32_bf16(af[mi], bfr[ni], acc[mi][ni], 0, 0, 0);
  }

  if (MODE == 0) {
#pragma unroll
    for (int ni = 0; ni < 4; ++ni) {
      int col = (int)nblk + wn + ni * 16 + l15;
      int which = col / 768;
      int rem = col - which * 768;
      int h = rem >> 6, d = rem & 63;
      float bcol = bias[col];
      if (which == 2) {
        short* vbase = qkv_out + (size_t)2 * HEADS * N_SEQ * HD
                     + ((size_t)h * HD + d) * N_SEQ;
#pragma unroll
        for (int mi = 0; mi < 4; ++mi) {
          int rowb = (int)mblk + wm + mi * 16 + g * 4;
          short4 o;
          o.x = f2bf(acc[mi][ni][0] + bcol);
          o.y = f2bf(acc[mi][ni][1] + bcol);
          o.z = f2bf(acc[mi][ni][2] + bcol);
          o.w = f2bf(acc[mi][ni][3] + bcol);
          *(short4*)(vbase + rowb) = o;
        }
      } else {
        float sc = (which == 0) ? QSCALE : 1.0f;
        short* dst = qkv_out + ((size_t)which * HEADS + h) * N_SEQ * HD + d;
#pragma unroll
        for (int mi = 0; mi < 4; ++mi) {
          int rowb = (int)mblk + wm + mi * 16 + g * 4;
#pragma unroll
          for (int r = 0; r < 4; ++r)
            dst[(size_t)(rowb + r) * HD] = f2bf((acc[mi][ni][r] + bcol) * sc);
        }
      }
    }
  } else {
#pragma unroll
    for (int ni = 0; ni < 4; ++ni) {
      int col = (int)nblk + wn + ni * 16 + l15;
      float bcol = bias[col];
#pragma unroll
      for (int mi = 0; mi < 4; ++mi) {
        int rowb = (int)mblk + wm + mi * 16 + g * 4;
#pragma unroll
        for (int r = 0; r < 4; ++r)
          c_out[(size_t)(rowb + r) * ldc + col] = acc[mi][ni][r] + bcol;
      }
    }
  }
}

// ---------------- kernel D: flash attention, 128 q-rows/block ----------------
// 4 waves, each owns 32 q-rows (2 m-frags). K/V frag reads amortized over 2x
// MFMA vs round-2. Q frags live in registers (no LDS staging). Static-max
// softmax (logits pre-scaled by log2e in GEMM1; exp2 never overflows).
#define AST 76   // LDS row stride: P-write quads hit disjoint banks {0,24,16,8}
__global__ __launch_bounds__(256) void attn_fa(const short* __restrict__ qkv_buf,
                                               short* __restrict__ out_bf) {
  __shared__ short Ks[64 * AST];
  __shared__ short Vs[64 * AST];   // transposed: Vs[d][n]
  __shared__ short Ps[128 * AST];  // 32 rows per wave
  int h = blockIdx.y;
  int q0 = blockIdx.x * 128;
  int tid = threadIdx.x, wave = tid >> 6, lane = tid & 63, g = lane >> 4, l15 = lane & 15;
  const short* qh  = qkv_buf + (size_t)(0 * HEADS + h) * N_SEQ * HD;
  const short* kh  = qkv_buf + (size_t)(1 * HEADS + h) * N_SEQ * HD;
  const short* vth = qkv_buf + (size_t)2 * HEADS * N_SEQ * HD + (size_t)h * HD * N_SEQ;

  // Q fragments straight from global (A-layout: row=l15, k=g*8+j)
  short8 qf[2][2];
#pragma unroll
  for (int mi = 0; mi < 2; ++mi)
#pragma unroll
    for (int kk = 0; kk < 2; ++kk)
      qf[mi][kk] = *(const short8*)(qh + (size_t)(q0 + wave * 32 + mi * 16 + l15) * HD
                                       + kk * 32 + g * 8);

  float l_r[2][4];
  f32x4 o_acc[2][4];
#pragma unroll
  for (int mi = 0; mi < 2; ++mi)
#pragma unroll
    for (int r = 0; r < 4; ++r) l_r[mi][r] = 0.f;
#pragma unroll
  for (int mi = 0; mi < 2; ++mi)
#pragma unroll
    for (int di = 0; di < 4; ++di)
#pragma unroll
      for (int r = 0; r < 4; ++r) o_acc[mi][di][r] = 0.f;

  int srow = tid >> 2;            // 0..63
  int scol = (tid & 3) * 16;      // 0,16,32,48  (two short8 per thread)

  // prologue: prefetch tile 0 into registers
  short8 kr0 = *(const short8*)(kh + (size_t)srow * HD + scol);
  short8 kr1 = *(const short8*)(kh + (size_t)srow * HD + scol + 8);
  short8 vr0 = *(const short8*)(vth + (size_t)srow * N_SEQ + scol);
  short8 vr1 = *(const short8*)(vth + (size_t)srow * N_SEQ + scol + 8);

  short* pw = Ps + wave * 32 * AST;

  for (int t0 = 0; t0 < N_SEQ; t0 += 64) {
    __syncthreads();   // previous tile's frag reads done
    *(short8*)(Ks + srow * AST + scol)     = kr0;
    *(short8*)(Ks + srow * AST + scol + 8) = kr1;
    *(short8*)(Vs + srow * AST + scol)     = vr0;
    *(short8*)(Vs + srow * AST + scol + 8) = vr1;
    __syncthreads();

    if (t0 + 64 < N_SEQ) {   // prefetch next tile (overlaps with MFMA below)
      int t1 = t0 + 64;
      kr0 = *(const short8*)(kh + (size_t)(t1 + srow) * HD + scol);
      kr1 = *(const short8*)(kh + (size_t)(t1 + srow) * HD + scol + 8);
      vr0 = *(const short8*)(vth + (size_t)srow * N_SEQ + t1 + scol);
      vr1 = *(const short8*)(vth + (size_t)srow * N_SEQ + t1 + scol + 8);
    }

    // S = Q K^T  (kf reused across both m-frags)
    f32x4 st[2][4];
#pragma unroll
    for (int mi = 0; mi < 2; ++mi)
#pragma unroll
      for (int ni = 0; ni < 4; ++ni)
#pragma unroll
        for (int r = 0; r < 4; ++r) st[mi][ni][r] = 0.f;
#pragma unroll
    for (int kk = 0; kk < 2; ++kk)
#pragma unroll
      for (int ni = 0; ni < 4; ++ni) {
        short8 kf = *(const short8*)(Ks + (ni * 16 + l15) * AST + kk * 32 + g * 8);
#pragma unroll
        for (int mi = 0; mi < 2; ++mi)
          st[mi][ni] = __builtin_amdgcn_mfma_f32_16x16x32_bf16(qf[mi][kk], kf, st[mi][ni], 0, 0, 0);
      }

    // p = exp2(s); row-sum per lane (cross-lane deferred to epilogue)
#pragma unroll
    for (int mi = 0; mi < 2; ++mi)
#pragma unroll
      for (int ni = 0; ni < 4; ++ni)
#pragma unroll
        for (int r = 0; r < 4; ++r) {
          float pv = __builtin_amdgcn_exp2f(st[mi][ni][r]);
          l_r[mi][r] += pv;
          pw[(mi * 16 + g * 4 + r) * AST + ni * 16 + l15] = f2bf_trunc(pv);
        }

    // O += P V  (vf reused across both m-frags)
#pragma unroll
    for (int kk = 0; kk < 2; ++kk) {
      short8 pf[2];
#pragma unroll
      for (int mi = 0; mi < 2; ++mi)
        pf[mi] = *(const short8*)(pw + (mi * 16 + l15) * AST + kk * 32 + g * 8);
#pragma unroll
      for (int di = 0; di < 4; ++di) {
        short8 vf = *(const short8*)(Vs + (di * 16 + l15) * AST + kk * 32 + g * 8);
#pragma unroll
        for (int mi = 0; mi < 2; ++mi)
          o_acc[mi][di] = __builtin_amdgcn_mfma_f32_16x16x32_bf16(pf[mi], vf, o_acc[mi][di], 0, 0, 0);
      }
    }
  }

  // deferred cross-lane row-sum reduction + store
#pragma unroll
  for (int mi = 0; mi < 2; ++mi)
#pragma unroll
    for (int r = 0; r < 4; ++r) {
      float s = l_r[mi][r];
      s += __shfl_xor(s, 1); s += __shfl_xor(s, 2);
      s += __shfl_xor(s, 4); s += __shfl_xor(s, 8);
      float inv = 1.0f / s;
      int qrow = q0 + wave * 32 + mi * 16 + g * 4 + r;
#pragma unroll
      for (int di = 0; di < 4; ++di)
        out_bf[(size_t)qrow * C_DIM + h * HD + di * 16 + l15] = f2bf(o_acc[mi][di][r] * inv);
    }
}

// ---------------- launcher ---------------------------------------------------
extern "C" void kernel_launch(void* const* d_in, const int* in_sizes, int n_in,
                              void* d_out, int out_size, void* d_ws, size_t ws_size,
                              hipStream_t stream) {
  const float* x        = (const float*)d_in[0];
  const float* tmpl     = (const float*)d_in[1];
  const float* coeffs   = (const float*)d_in[2];
  const float* qkv_bias = (const float*)d_in[3];
  const float* proj_w   = (const float*)d_in[4];
  const float* proj_b   = (const float*)d_in[5];
  float* out = (float*)d_out;
  char* ws = (char*)d_ws;

  short* w_bf    = (short*)(ws);                 // 2304*768       (3,538,944 B)
  short* x_bf    = (short*)(ws + 3538944);       // 4096*768       (6,291,456 B)
  short* pw_bf   = (short*)(ws + 9830400);       // 768*768        (1,179,648 B)
  short* qkvb    = (short*)(ws + 11010048);      // 3*12*4096*64   (18,874,368 B), v transposed
  short* attn_bf = (short*)(ws + 29884416);      // 4096*768       (6,291,456 B)

  prep_qkvw<<<1728, 256, 0, stream>>>(tmpl, coeffs, w_bf);
  cvt_bf16<<<3072, 256, 0, stream>>>(x, x_bf, 786432);
  cvt_bf16<<<576, 256, 0, stream>>>(proj_w, pw_bf, 147456);

  dim3 g1(32, 18);
  gemm_bt<0><<<g1, 256, 0, stream>>>(x_bf, w_bf, qkv_bias, qkvb, nullptr, 768, 0);

  dim3 ga(32, 12);
  attn_fa<<<ga, 256, 0, stream>>>(qkvb, attn_bf);

  dim3 g2(32, 6);
  gemm_bt<1><<<g2, 256, 0, stream>>>(attn_bf, pw_bf, proj_b, nullptr, out, 768, 768);
}

// Round 4
// 349.303 us; speedup vs baseline: 1.1577x; 1.1577x over previous
//
#include <hip/hip_runtime.h>
#include <stdint.h>

#define N_SEQ 4096
#define C_DIM 768
#define HEADS 12
#define HD    64
#define OI    (2304*768)

typedef __attribute__((ext_vector_type(8))) short short8;
typedef __attribute__((ext_vector_type(4))) float f32x4;
typedef __attribute__((ext_vector_type(16))) float f32x16;

__device__ __forceinline__ short f2bf(float f) {
  union { float f; unsigned u; } v; v.f = f;
  unsigned r = v.u + 0x7FFF + ((v.u >> 16) & 1);   // RNE
  return (short)(r >> 16);
}
__device__ __forceinline__ short f2bf_trunc(float f) {
  union { float f; unsigned u; } v; v.f = f;
  return (short)(v.u >> 16);                       // truncate (p>0, err<0.4%)
}

// ---------------- kernel A: combine templates -> bf16 qkv_w (2304x768) -------
__global__ __launch_bounds__(256) void prep_qkvw(const float* __restrict__ tmpl,
                                                 const float* __restrict__ coeffs,
                                                 short* __restrict__ w_bf) {
  __shared__ float c[16];
  if (threadIdx.x < 16)
    c[threadIdx.x] = 0.5f * (coeffs[threadIdx.x] + coeffs[16 + threadIdx.x]);
  __syncthreads();
  int idx = blockIdx.x * 256 + threadIdx.x;
  int base = idx * 4;
  if (base >= OI) return;
  float ax = 0.f, ay = 0.f, az = 0.f, aw = 0.f;
#pragma unroll
  for (int t = 0; t < 16; ++t) {
    float4 v = *(const float4*)(tmpl + (size_t)t * OI + base);
    float ct = c[t];
    ax = fmaf(ct, v.x, ax); ay = fmaf(ct, v.y, ay);
    az = fmaf(ct, v.z, az); aw = fmaf(ct, v.w, aw);
  }
  short4 o = make_short4(f2bf(ax), f2bf(ay), f2bf(az), f2bf(aw));
  *(short4*)(w_bf + base) = o;
}

// ---------------- kernel B: fp32 -> bf16 cast (n4 float4 groups) -------------
__global__ __launch_bounds__(256) void cvt_bf16(const float* __restrict__ src,
                                                short* __restrict__ dst, int n4) {
  int i = blockIdx.x * 256 + threadIdx.x;
  if (i >= n4) return;
  float4 v = ((const float4*)src)[i];
  ((short4*)dst)[i] = make_short4(f2bf(v.x), f2bf(v.y), f2bf(v.z), f2bf(v.w));
}

// ---------------- kernel C: 128x128 bf16 MFMA GEMM (QKV projection) ----------
// q -> [h][n][d] pre-scaled 0.125*log2e, k -> [h][n][d], v -> TRANSPOSED [h][d][n]
#define GST 40
#define QSCALE 0.1803368801111204f   // 0.125 * log2(e)
__global__ __launch_bounds__(256) void gemm_qkv(const short* __restrict__ A,
                                                const short* __restrict__ B,
                                                const float* __restrict__ bias,
                                                short* __restrict__ qkv_out) {
  __shared__ short As[128 * GST];
  __shared__ short Bs[128 * GST];
  int tid = threadIdx.x;
  int wave = tid >> 6, lane = tid & 63, g = lane >> 4, l15 = lane & 15;
  int wm = (wave >> 1) * 64, wn = (wave & 1) * 64;
  size_t mblk = (size_t)blockIdx.x * 128;
  size_t nblk = (size_t)blockIdx.y * 128;

  f32x4 acc[4][4];
#pragma unroll
  for (int mi = 0; mi < 4; ++mi)
#pragma unroll
    for (int ni = 0; ni < 4; ++ni)
#pragma unroll
      for (int r = 0; r < 4; ++r) acc[mi][ni][r] = 0.f;

  int row0 = tid >> 2;
  int c8   = (tid & 3) * 8;

  for (int k0 = 0; k0 < 768; k0 += 32) {
    short8 a0 = *(const short8*)(A + (mblk + row0) * 768 + k0 + c8);
    short8 a1 = *(const short8*)(A + (mblk + row0 + 64) * 768 + k0 + c8);
    short8 b0 = *(const short8*)(B + (nblk + row0) * 768 + k0 + c8);
    short8 b1 = *(const short8*)(B + (nblk + row0 + 64) * 768 + k0 + c8);
    __syncthreads();
    *(short8*)(As + row0 * GST + c8) = a0;
    *(short8*)(As + (row0 + 64) * GST + c8) = a1;
    *(short8*)(Bs + row0 * GST + c8) = b0;
    *(short8*)(Bs + (row0 + 64) * GST + c8) = b1;
    __syncthreads();
    short8 af[4], bfr[4];
#pragma unroll
    for (int mi = 0; mi < 4; ++mi)
      af[mi] = *(const short8*)(As + (wm + mi * 16 + l15) * GST + g * 8);
#pragma unroll
    for (int ni = 0; ni < 4; ++ni)
      bfr[ni] = *(const short8*)(Bs + (wn + ni * 16 + l15) * GST + g * 8);
#pragma unroll
    for (int mi = 0; mi < 4; ++mi)
#pragma unroll
      for (int ni = 0; ni < 4; ++ni)
        acc[mi][ni] = __builtin_amdgcn_mfma_f32_16x16x32_bf16(af[mi], bfr[ni], acc[mi][ni], 0, 0, 0);
  }

#pragma unroll
  for (int ni = 0; ni < 4; ++ni) {
    int col = (int)nblk + wn + ni * 16 + l15;
    int which = col / 768;
    int rem = col - which * 768;
    int h = rem >> 6, d = rem & 63;
    float bcol = bias[col];
    if (which == 2) {
      short* vbase = qkv_out + (size_t)2 * HEADS * N_SEQ * HD
                   + ((size_t)h * HD + d) * N_SEQ;
#pragma unroll
      for (int mi = 0; mi < 4; ++mi) {
        int rowb = (int)mblk + wm + mi * 16 + g * 4;
        short4 o;
        o.x = f2bf(acc[mi][ni][0] + bcol);
        o.y = f2bf(acc[mi][ni][1] + bcol);
        o.z = f2bf(acc[mi][ni][2] + bcol);
        o.w = f2bf(acc[mi][ni][3] + bcol);
        *(short4*)(vbase + rowb) = o;
      }
    } else {
      float sc = (which == 0) ? QSCALE : 1.0f;
      short* dst = qkv_out + ((size_t)which * HEADS + h) * N_SEQ * HD + d;
#pragma unroll
      for (int mi = 0; mi < 4; ++mi) {
        int rowb = (int)mblk + wm + mi * 16 + g * 4;
#pragma unroll
        for (int r = 0; r < 4; ++r)
          dst[(size_t)(rowb + r) * HD] = f2bf((acc[mi][ni][r] + bcol) * sc);
      }
    }
  }
}

// ---------------- kernel E: 64x64 bf16 GEMM, fp32 out + bias (proj) ----------
__global__ __launch_bounds__(256) void gemm_proj(const short* __restrict__ A,
                                                 const short* __restrict__ B,
                                                 const float* __restrict__ bias,
                                                 float* __restrict__ C) {
  __shared__ short As[64 * GST];
  __shared__ short Bs[64 * GST];
  int tid = threadIdx.x;
  int wave = tid >> 6, lane = tid & 63, g = lane >> 4, l15 = lane & 15;
  int wm = (wave >> 1) * 32, wn = (wave & 1) * 32;
  size_t mblk = (size_t)blockIdx.x * 64;
  size_t nblk = (size_t)blockIdx.y * 64;

  f32x4 acc[2][2];
#pragma unroll
  for (int mi = 0; mi < 2; ++mi)
#pragma unroll
    for (int ni = 0; ni < 2; ++ni)
#pragma unroll
      for (int r = 0; r < 4; ++r) acc[mi][ni][r] = 0.f;

  int row0 = tid >> 2;
  int c8   = (tid & 3) * 8;

  for (int k0 = 0; k0 < 768; k0 += 32) {
    short8 a0 = *(const short8*)(A + (mblk + row0) * 768 + k0 + c8);
    short8 b0 = *(const short8*)(B + (nblk + row0) * 768 + k0 + c8);
    __syncthreads();
    *(short8*)(As + row0 * GST + c8) = a0;
    *(short8*)(Bs + row0 * GST + c8) = b0;
    __syncthreads();
    short8 af[2], bfr[2];
#pragma unroll
    for (int mi = 0; mi < 2; ++mi)
      af[mi] = *(const short8*)(As + (wm + mi * 16 + l15) * GST + g * 8);
#pragma unroll
    for (int ni = 0; ni < 2; ++ni)
      bfr[ni] = *(const short8*)(Bs + (wn + ni * 16 + l15) * GST + g * 8);
#pragma unroll
    for (int mi = 0; mi < 2; ++mi)
#pragma unroll
      for (int ni = 0; ni < 2; ++ni)
        acc[mi][ni] = __builtin_amdgcn_mfma_f32_16x16x32_bf16(af[mi], bfr[ni], acc[mi][ni], 0, 0, 0);
  }

#pragma unroll
  for (int ni = 0; ni < 2; ++ni) {
    int col = (int)nblk + wn + ni * 16 + l15;
    float bcol = bias[col];
#pragma unroll
    for (int mi = 0; mi < 2; ++mi) {
      int rowb = (int)mblk + wm + mi * 16 + g * 4;
#pragma unroll
      for (int r = 0; r < 4; ++r)
        C[(size_t)(rowb + r) * 768 + col] = acc[mi][ni][r] + bcol;
    }
  }
}

// ---------------- kernel D: flash attention, 32x32 MFMA, transposed-S --------
// 2 waves/block, 64 q-rows/block (32/wave). S^T = K*Q^T so softmax cols are
// lane-resident (q=lane&31) -> P stores are short4, P-frag reads b128.
// Static-max softmax (scale*log2e folded into q by gemm_qkv).
#define PST 68
__global__ __launch_bounds__(128) void attn_fa(const short* __restrict__ qkv_buf,
                                               short* __restrict__ out_bf) {
  __shared__ short Ks[64 * PST];   // [kv][d]
  __shared__ short Vt[64 * PST];   // [d][kv]
  __shared__ short Ps[2 * 32 * PST];
  __shared__ float ls[64];
  int h = blockIdx.y;
  int q0 = blockIdx.x * 64;
  int tid = threadIdx.x, wave = tid >> 6, lane = tid & 63;
  int q5 = lane & 31, h5 = lane >> 5;
  const short* qh  = qkv_buf + (size_t)(0 * HEADS + h) * N_SEQ * HD;
  const short* kh  = qkv_buf + (size_t)(1 * HEADS + h) * N_SEQ * HD;
  const short* vth = qkv_buf + (size_t)2 * HEADS * N_SEQ * HD + (size_t)h * HD * N_SEQ;

  // Q B-frags from global: B[k=d][n=q]: n=lane&31, k=h5*8+j (+16c)
  short8 qf[4];
#pragma unroll
  for (int c = 0; c < 4; ++c)
    qf[c] = *(const short8*)(qh + (size_t)(q0 + wave * 32 + q5) * HD + c * 16 + h5 * 8);

  f32x16 o_acc[2];
#pragma unroll
  for (int dt = 0; dt < 2; ++dt)
#pragma unroll
    for (int r = 0; r < 16; ++r) o_acc[dt][r] = 0.f;
  float l_r = 0.f;

  int srow = tid >> 1;             // 0..63
  int shalf = (tid & 1) * 32;      // 0 or 32

  // prefetch tile 0
  short8 kr[4], vr[4];
#pragma unroll
  for (int i = 0; i < 4; ++i) {
    kr[i] = *(const short8*)(kh + (size_t)srow * HD + shalf + 8 * i);
    vr[i] = *(const short8*)(vth + (size_t)srow * N_SEQ + shalf + 8 * i);
  }

  short* pw = Ps + wave * 32 * PST;

  for (int t0 = 0; t0 < N_SEQ; t0 += 64) {
    __syncthreads();
#pragma unroll
    for (int i = 0; i < 4; ++i) {
      *(short8*)(Ks + srow * PST + shalf + 8 * i) = kr[i];
      *(short8*)(Vt + srow * PST + shalf + 8 * i) = vr[i];
    }
    __syncthreads();

    if (t0 + 64 < N_SEQ) {
      int t1 = t0 + 64;
#pragma unroll
      for (int i = 0; i < 4; ++i) {
        kr[i] = *(const short8*)(kh + (size_t)(t1 + srow) * HD + shalf + 8 * i);
        vr[i] = *(const short8*)(vth + (size_t)srow * N_SEQ + t1 + shalf + 8 * i);
      }
    }

    // S^T = K * Q^T : D[kv][q], 2 kv-tiles of 32
    f32x16 st[2];
#pragma unroll
    for (int kt = 0; kt < 2; ++kt)
#pragma unroll
      for (int r = 0; r < 16; ++r) st[kt][r] = 0.f;
#pragma unroll
    for (int c = 0; c < 4; ++c)
#pragma unroll
      for (int kt = 0; kt < 2; ++kt) {
        short8 kf = *(const short8*)(Ks + (kt * 32 + q5) * PST + c * 16 + h5 * 8);
        st[kt] = __builtin_amdgcn_mfma_f32_32x32x16_bf16(kf, qf[c], st[kt], 0, 0, 0);
      }

    // p = exp2(s); lane-local row-sum (lane owns col q, half the kv rows)
#pragma unroll
    for (int kt = 0; kt < 2; ++kt)
#pragma unroll
      for (int cc = 0; cc < 4; ++cc) {
        float p0 = __builtin_amdgcn_exp2f(st[kt][cc * 4 + 0]);
        float p1 = __builtin_amdgcn_exp2f(st[kt][cc * 4 + 1]);
        float p2 = __builtin_amdgcn_exp2f(st[kt][cc * 4 + 2]);
        float p3 = __builtin_amdgcn_exp2f(st[kt][cc * 4 + 3]);
        l_r += (p0 + p1) + (p2 + p3);
        short4 o = make_short4(f2bf_trunc(p0), f2bf_trunc(p1), f2bf_trunc(p2), f2bf_trunc(p3));
        // P[q][kv]: kv = kt*32 + cc*8 + h5*4 + r
        *(short4*)(pw + q5 * PST + kt * 32 + cc * 8 + h5 * 4) = o;
      }

    // O += P V : A = P[m=q][k=kv] (b128), B = V[k=kv][n=d] from Vt[d][kv]
#pragma unroll
    for (int c = 0; c < 4; ++c) {
      short8 pf = *(const short8*)(pw + q5 * PST + c * 16 + h5 * 8);
#pragma unroll
      for (int dt = 0; dt < 2; ++dt) {
        short8 vf = *(const short8*)(Vt + (dt * 32 + q5) * PST + c * 16 + h5 * 8);
        o_acc[dt] = __builtin_amdgcn_mfma_f32_32x32x16_bf16(pf, vf, o_acc[dt], 0, 0, 0);
      }
    }
  }

  // full row-sum: own half + partner half (lane^32 has same q, other kv half)
  l_r += __shfl_xor(l_r, 32);
  if (h5 == 0) ls[wave * 32 + q5] = 1.0f / l_r;
  __syncthreads();   // cheap: once per kernel; waves independent but safe

  // O epilogue: o_acc[dt] reg r -> O[q=(r&3)+8*(r>>2)+4*h5][d=dt*32+q5]
#pragma unroll
  for (int cc = 0; cc < 4; ++cc)
#pragma unroll
    for (int rr = 0; rr < 4; ++rr) {
      int qloc = rr + 8 * cc + 4 * h5;
      float inv = ls[wave * 32 + qloc];
      int qrow = q0 + wave * 32 + qloc;
#pragma unroll
      for (int dt = 0; dt < 2; ++dt)
        out_bf[(size_t)qrow * C_DIM + h * HD + dt * 32 + q5] =
            f2bf(o_acc[dt][cc * 4 + rr] * inv);
    }
}

// ---------------- launcher ---------------------------------------------------
extern "C" void kernel_launch(void* const* d_in, const int* in_sizes, int n_in,
                              void* d_out, int out_size, void* d_ws, size_t ws_size,
                              hipStream_t stream) {
  const float* x        = (const float*)d_in[0];
  const float* tmpl     = (const float*)d_in[1];
  const float* coeffs   = (const float*)d_in[2];
  const float* qkv_bias = (const float*)d_in[3];
  const float* proj_w   = (const float*)d_in[4];
  const float* proj_b   = (const float*)d_in[5];
  float* out = (float*)d_out;
  char* ws = (char*)d_ws;

  short* w_bf    = (short*)(ws);                 // 2304*768
  short* x_bf    = (short*)(ws + 3538944);       // 4096*768
  short* pw_bf   = (short*)(ws + 9830400);       // 768*768
  short* qkvb    = (short*)(ws + 11010048);      // 3*12*4096*64 (v transposed)
  short* attn_bf = (short*)(ws + 29884416);      // 4096*768

  prep_qkvw<<<1728, 256, 0, stream>>>(tmpl, coeffs, w_bf);
  cvt_bf16<<<3072, 256, 0, stream>>>(x, x_bf, 786432);
  cvt_bf16<<<576, 256, 0, stream>>>(proj_w, pw_bf, 147456);

  dim3 g1(32, 18);
  gemm_qkv<<<g1, 256, 0, stream>>>(x_bf, w_bf, qkv_bias, qkvb);

  dim3 ga(64, 12);
  attn_fa<<<ga, 128, 0, stream>>>(qkvb, attn_bf);

  dim3 g2(64, 12);
  gemm_proj<<<g2, 256, 0, stream>>>(attn_bf, pw_bf, proj_b, out);
}